// Round 1
// baseline (545.786 us; speedup 1.0000x reference)
//
#include <hip/hip_runtime.h>
#include <math.h>

#define EMBED 1024
#define HIDDEN 4096
#define ROWS_CAP 3072

typedef short short8 __attribute__((ext_vector_type(8)));
typedef float f32x4 __attribute__((ext_vector_type(4)));

__device__ __forceinline__ short f2bf(float f) {
  __bf16 h = (__bf16)f;
  return __builtin_bit_cast(short, h);
}

__device__ __forceinline__ short8 pack8(float4 a, float4 b) {
  short8 r;
  r[0] = f2bf(a.x); r[1] = f2bf(a.y); r[2] = f2bf(a.z); r[3] = f2bf(a.w);
  r[4] = f2bf(b.x); r[5] = f2bf(b.y); r[6] = f2bf(b.z); r[7] = f2bf(b.w);
  return r;
}

// ---------------- router: logits -> softmax -> top2 -> counts ----------------
__global__ __launch_bounds__(256) void router_kernel(
    const float* __restrict__ x, const float* __restrict__ gw,
    int* __restrict__ count, int2* __restrict__ t_idx, float2* __restrict__ t_w) {
  int t = blockIdx.x * 4 + (threadIdx.x >> 6);
  int lane = threadIdx.x & 63;
  const float* xr = x + (size_t)t * EMBED;
  float acc[8] = {0.f,0.f,0.f,0.f,0.f,0.f,0.f,0.f};
#pragma unroll
  for (int c = 0; c < 4; ++c) {
    float4 xv = *(const float4*)(xr + lane * 4 + c * 256);
#pragma unroll
    for (int e = 0; e < 8; ++e) {
      float4 gv = *(const float4*)(gw + e * EMBED + lane * 4 + c * 256);
      acc[e] += xv.x * gv.x + xv.y * gv.y + xv.z * gv.z + xv.w * gv.w;
    }
  }
#pragma unroll
  for (int e = 0; e < 8; ++e) {
#pragma unroll
    for (int off = 32; off > 0; off >>= 1) acc[e] += __shfl_down(acc[e], off);
  }
  if (lane == 0) {
    float m = acc[0];
#pragma unroll
    for (int e = 1; e < 8; ++e) m = fmaxf(m, acc[e]);
    float p[8]; float s = 0.f;
#pragma unroll
    for (int e = 0; e < 8; ++e) { p[e] = expf(acc[e] - m); s += p[e]; }
    float inv = 1.0f / s;
#pragma unroll
    for (int e = 0; e < 8; ++e) p[e] *= inv;
    int i0 = 0; float p0 = p[0];
#pragma unroll
    for (int e = 1; e < 8; ++e) if (p[e] > p0) { p0 = p[e]; i0 = e; }
    int i1 = -1; float p1 = -1.f;
#pragma unroll
    for (int e = 0; e < 8; ++e) if (e != i0 && p[e] > p1) { p1 = p[e]; i1 = e; }
    float denom = p0 + p1 + 1e-9f;
    float w0 = p0 / denom, w1 = p1 / denom;
    atomicAdd(&count[i0], 1);
    atomicAdd(&count[i1], 1);
    t_idx[t] = make_int2(i0, i1);
    t_w[t] = make_float2(w0, w1);
  }
}

// ---------------- assign: 128-aligned bases + compact row map ----------------
__global__ __launch_bounds__(256) void assign_kernel(
    const int* __restrict__ count, int* __restrict__ base,
    const int2* __restrict__ t_idx, const float2* __restrict__ t_w,
    int* __restrict__ row_token, float* __restrict__ row_w, int T) {
  __shared__ int s_base[8];
  __shared__ int s_cur[8];
  int tid = threadIdx.x;
  for (int i = tid; i < ROWS_CAP; i += 256) row_token[i] = -1;
  if (tid == 0) {
    int b = 0;
    for (int e = 0; e < 8; ++e) {
      s_base[e] = b; base[e] = b;
      b += (count[e] + 127) & ~127;
    }
  }
  if (tid < 8) s_cur[tid] = 0;
  __syncthreads();
  for (int t = tid; t < T; t += 256) {
    int2 ii = t_idx[t]; float2 ww = t_w[t];
    int p = atomicAdd(&s_cur[ii.x], 1);
    int r = s_base[ii.x] + p;
    row_token[r] = t; row_w[r] = ww.x;
    p = atomicAdd(&s_cur[ii.y], 1);
    r = s_base[ii.y] + p;
    row_token[r] = t; row_w[r] = ww.y;
  }
}

// ---------------- FFN layer 1: H = gelu(X_e @ W1[e] + b1[e]) ----------------
// grid (32, 64): x = n-tile (128 wide over HIDDEN), y = e*8 + m-tile
__global__ __launch_bounds__(256) void ffn1_kernel(
    const float* __restrict__ x, const float* __restrict__ w1,
    const float* __restrict__ b1, const int* __restrict__ count,
    const int* __restrict__ base, const int* __restrict__ row_token,
    unsigned short* __restrict__ H) {
  int nt = blockIdx.x;
  int e  = blockIdx.y >> 3;
  int mt = blockIdx.y & 7;
  int cnt = count[e];
  if (mt * 128 >= cnt) return;
  int base_e = base[e];
  int n0 = nt * 128;
  const float* w1e = w1 + (size_t)e * EMBED * HIDDEN;

  __shared__ __align__(16) short As[128 * 40];
  __shared__ __align__(16) short Bs[128 * 40];

  int tid = threadIdx.x;
  // A staging: 2 threads per row, 16 k-elems each
  int arow = tid >> 1;
  int akq  = (tid & 1) * 16;
  int a_pos = mt * 128 + arow;
  int a_tok = (a_pos < cnt) ? row_token[base_e + a_pos] : -1;
  const float* a_src = x + (size_t)(a_tok < 0 ? 0 : a_tok) * EMBED + akq;
  short* As_dst = &As[arow * 40 + akq];
  // B staging: coalesced along n, strided over k; LDS layout [n][k] k-contig
  int bn  = tid & 127;
  int bk0 = (tid >> 7) * 16;
  const float* b_src = w1e + (size_t)(n0 + bn);
  short* Bs_dst = &Bs[bn * 40 + bk0];

  int lane = tid & 63, wv = tid >> 6;
  int quad = lane >> 4, l15 = lane & 15;
  const short* Abase = &As[((wv & 1) * 64 + l15) * 40 + quad * 8];
  const short* Bbase = &Bs[((wv >> 1) * 64 + l15) * 40 + quad * 8];

  f32x4 acc[4][4];
#pragma unroll
  for (int i = 0; i < 4; ++i)
#pragma unroll
    for (int j = 0; j < 4; ++j) acc[i][j] = (f32x4){0.f, 0.f, 0.f, 0.f};

  for (int kk = 0; kk < EMBED; kk += 32) {
    short8 av0 = {0,0,0,0,0,0,0,0}, av1 = {0,0,0,0,0,0,0,0};
    if (a_tok >= 0) {
      const float4* p = (const float4*)(a_src + kk);
      float4 v0 = p[0], v1 = p[1], v2 = p[2], v3 = p[3];
      av0 = pack8(v0, v1); av1 = pack8(v2, v3);
    }
    float bv[16];
#pragma unroll
    for (int j = 0; j < 16; ++j) bv[j] = b_src[(size_t)(kk + bk0 + j) * HIDDEN];
    short8 blo, bhi;
#pragma unroll
    for (int j = 0; j < 8; ++j) { blo[j] = f2bf(bv[j]); bhi[j] = f2bf(bv[j + 8]); }

    *(short8*)As_dst = av0; *(short8*)(As_dst + 8) = av1;
    *(short8*)Bs_dst = blo; *(short8*)(Bs_dst + 8) = bhi;
    __syncthreads();

    short8 af[4], bfv[4];
#pragma unroll
    for (int i = 0; i < 4; ++i) {
      af[i]  = *(const short8*)(Abase + i * 16 * 40);
      bfv[i] = *(const short8*)(Bbase + i * 16 * 40);
    }
#pragma unroll
    for (int i = 0; i < 4; ++i)
#pragma unroll
      for (int j = 0; j < 4; ++j)
        acc[i][j] = __builtin_amdgcn_mfma_f32_16x16x32_bf16(af[i], bfv[j], acc[i][j], 0, 0, 0);
    __syncthreads();
  }

  const float* b1e = b1 + e * HIDDEN;
#pragma unroll
  for (int i = 0; i < 4; ++i) {
    int rl = (wv & 1) * 64 + i * 16 + quad * 4;
#pragma unroll
    for (int rg = 0; rg < 4; ++rg) {
      int pos = mt * 128 + rl + rg;
      if (pos < cnt) {
        unsigned short* hrow = H + (size_t)(base_e + pos) * HIDDEN;
#pragma unroll
        for (int j = 0; j < 4; ++j) {
          int col = n0 + (wv >> 1) * 64 + j * 16 + l15;
          float v = acc[i][j][rg] + b1e[col];
          float g = 0.5f * v * (1.0f + erff(v * 0.70710678118654752f));
          hrow[col] = (unsigned short)f2bf(g);
        }
      }
    }
  }
}

// ---------------- FFN layer 2: out += w_r * (H_e @ W2[e] + b2[e]) ----------------
// grid (16, 64): x = n-tile (64 wide over EMBED), y = e*8 + m-tile
__global__ __launch_bounds__(256) void ffn2_kernel(
    const unsigned short* __restrict__ H, const float* __restrict__ w2,
    const float* __restrict__ b2, const int* __restrict__ count,
    const int* __restrict__ base, const int* __restrict__ row_token,
    const float* __restrict__ row_w, float* __restrict__ out) {
  int nt = blockIdx.x;
  int e  = blockIdx.y >> 3;
  int mt = blockIdx.y & 7;
  int cnt = count[e];
  if (mt * 128 >= cnt) return;
  int base_e = base[e];
  int n0 = nt * 64;
  const float* w2e = w2 + (size_t)e * HIDDEN * EMBED;

  __shared__ __align__(16) short As[128 * 40];
  __shared__ __align__(16) short Bs[64 * 40];

  int tid = threadIdx.x;
  int arow = tid >> 1;
  int akq  = (tid & 1) * 16;
  int a_pos = mt * 128 + arow;
  bool a_ok = (a_pos < cnt);
  const unsigned short* a_src = H + (size_t)(base_e + (a_ok ? a_pos : 0)) * HIDDEN + akq;
  short* As_dst = &As[arow * 40 + akq];

  int bn  = tid & 63;
  int bk0 = (tid >> 6) * 8;
  const float* b_src = w2e + (size_t)(n0 + bn);
  short* Bs_dst = &Bs[bn * 40 + bk0];

  int lane = tid & 63, wv = tid >> 6;
  int quad = lane >> 4, l15 = lane & 15;
  const short* Abase = &As[((wv & 1) * 64 + l15) * 40 + quad * 8];
  const short* Bbase = &Bs[((wv >> 1) * 32 + l15) * 40 + quad * 8];

  f32x4 acc[4][2];
#pragma unroll
  for (int i = 0; i < 4; ++i)
#pragma unroll
    for (int j = 0; j < 2; ++j) acc[i][j] = (f32x4){0.f, 0.f, 0.f, 0.f};

  for (int kk = 0; kk < HIDDEN; kk += 32) {
    short8 av0 = {0,0,0,0,0,0,0,0}, av1 = {0,0,0,0,0,0,0,0};
    if (a_ok) {
      const short8* p = (const short8*)(a_src + kk);
      av0 = p[0]; av1 = p[1];
    }
    float bv[8];
#pragma unroll
    for (int j = 0; j < 8; ++j) bv[j] = b_src[(size_t)(kk + bk0 + j) * EMBED];
    short8 bpk;
#pragma unroll
    for (int j = 0; j < 8; ++j) bpk[j] = f2bf(bv[j]);

    *(short8*)As_dst = av0; *(short8*)(As_dst + 8) = av1;
    *(short8*)Bs_dst = bpk;
    __syncthreads();

    short8 af[4], bfv[2];
#pragma unroll
    for (int i = 0; i < 4; ++i) af[i] = *(const short8*)(Abase + i * 16 * 40);
#pragma unroll
    for (int j = 0; j < 2; ++j) bfv[j] = *(const short8*)(Bbase + j * 16 * 40);
#pragma unroll
    for (int i = 0; i < 4; ++i)
#pragma unroll
      for (int j = 0; j < 2; ++j)
        acc[i][j] = __builtin_amdgcn_mfma_f32_16x16x32_bf16(af[i], bfv[j], acc[i][j], 0, 0, 0);
    __syncthreads();
  }

  const float* b2e = b2 + e * EMBED;
#pragma unroll
  for (int i = 0; i < 4; ++i) {
    int rl = (wv & 1) * 64 + i * 16 + quad * 4;
#pragma unroll
    for (int rg = 0; rg < 4; ++rg) {
      int pos = mt * 128 + rl + rg;
      if (pos < cnt) {
        int r = base_e + pos;
        int tok = row_token[r];
        float wgt = row_w[r];
        float* orow = out + (size_t)tok * EMBED;
#pragma unroll
        for (int j = 0; j < 2; ++j) {
          int col = n0 + (wv >> 1) * 32 + j * 16 + l15;
          float v = (acc[i][j][rg] + b2e[col]) * wgt;
          atomicAdd(orow + col, v);
        }
      }
    }
  }
}

extern "C" void kernel_launch(void* const* d_in, const int* in_sizes, int n_in,
                              void* d_out, int out_size, void* d_ws, size_t ws_size,
                              hipStream_t stream) {
  (void)n_in; (void)ws_size;
  const float* x   = (const float*)d_in[0];
  const float* gw  = (const float*)d_in[1];
  const float* w1  = (const float*)d_in[2];
  const float* b1  = (const float*)d_in[3];
  const float* w2  = (const float*)d_in[4];
  const float* b2  = (const float*)d_in[5];
  float* out = (float*)d_out;
  int T = in_sizes[0] / EMBED;  // 1024

  char* w = (char*)d_ws;
  int*    count     = (int*)(w + 0);        // 8 ints
  int*    base      = (int*)(w + 32);       // 8 ints
  int2*   t_idx     = (int2*)(w + 1024);    // T int2
  float2* t_w       = (float2*)(w + 1024 + 8192);
  int*    row_token = (int*)(w + 32768);    // ROWS_CAP ints
  float*  row_w     = (float*)(w + 49152);  // ROWS_CAP floats
  unsigned short* H = (unsigned short*)(w + 65536);  // ROWS_CAP x HIDDEN bf16

  hipMemsetAsync(count, 0, 32, stream);
  hipMemsetAsync(out, 0, (size_t)out_size * sizeof(float), stream);
  router_kernel<<<T / 4, 256, 0, stream>>>(x, gw, count, t_idx, t_w);
  assign_kernel<<<1, 256, 0, stream>>>(count, base, t_idx, t_w, row_token, row_w, T);
  ffn1_kernel<<<dim3(HIDDEN / 128, 64), 256, 0, stream>>>(x, w1, b1, count, base, row_token, H);
  ffn2_kernel<<<dim3(EMBED / 64, 64), 256, 0, stream>>>(H, w2, b2, count, base, row_token, row_w, out);
}